// Round 14
// baseline (240.716 us; speedup 1.0000x reference)
//
#include <hip/hip_runtime.h>

#define NB 256      // batch
#define TT 200      // time steps
#define DD 1250     // input dim
#define H1 100
#define H2 20
#define NO 2

// ---- GEMM kernel geometry: C[51200,100] = Xflat[51200,1250] @ Wih1^T ----
#define BM 64                 // rows per block
#define GRID_A (51200 / BM)   // 800
#define KC 64                 // K-chunk
#define NCH 20                // ceil(1250/64) -> 1280 padded
#define WR 112                // padded W rows (7 n-tiles of 16)
#define PIT 72                // LDS row pitch in shorts (2-way bank free)
#define KPAD 1280

typedef __attribute__((ext_vector_type(4))) float f32x4;
typedef __attribute__((ext_vector_type(8))) short s16x8;

__device__ __forceinline__ unsigned short f2bf(float f) {
    unsigned u = __builtin_bit_cast(unsigned, f);
    u += 0x7FFFu + ((u >> 16) & 1u);          // round-to-nearest-even
    return (unsigned short)(u >> 16);
}
__device__ __forceinline__ float bf2f(unsigned short s) {
    unsigned u = ((unsigned)s) << 16;
    return __builtin_bit_cast(float, u);
}

// ============ kernel 0: Wih1 fp32[100][1250] -> bf16 [112][1280] (padded) ====
__global__ void prep_w(const float* __restrict__ Wih1, unsigned short* __restrict__ w_ws)
{
    const int idx = blockIdx.x * 256 + threadIdx.x;     // uint2 (4-short) granules
    if (idx >= WR * KPAD / 4) return;
    const int r  = idx / (KPAD / 4);
    const int k4 = (idx - r * (KPAD / 4)) * 4;
    unsigned short o[4];
    #pragma unroll
    for (int e = 0; e < 4; ++e) {
        const int k = k4 + e;
        o[e] = (r < H1 && k < DD) ? f2bf(Wih1[r * DD + k]) : (unsigned short)0;
    }
    uint2 pk;
    pk.x = (unsigned)o[0] | ((unsigned)o[1] << 16);
    pk.y = (unsigned)o[2] | ((unsigned)o[3] << 16);
    *(uint2*)&w_ws[r * KPAD + k4] = pk;
}

// ============ kernel 1: pre1[b*TT+t][h] (bf16, ROW-major) via MFMA ===========
__launch_bounds__(256, 4)
__global__ void gemm_pre(const float* __restrict__ x,
                         const unsigned short* __restrict__ w_ws,
                         unsigned short* __restrict__ preT)
{
    __shared__ __align__(16) unsigned short a_s[BM * PIT];   //  9216 B
    __shared__ __align__(16) unsigned short w_s[WR * PIT];   // 16128 B

    const int tid = threadIdx.x;
    const int bid = blockIdx.x;
    const int wv  = tid >> 6;
    const int ln  = tid & 63;
    const int c16 = ln & 15;
    const int kg  = (ln >> 4) << 3;

    f32x4 acc[7];
    #pragma unroll
    for (int i = 0; i < 7; ++i)
        #pragma unroll
        for (int c = 0; c < 4; ++c) acc[i][c] = 0.f;

    for (int kc = 0; kc < NCH; ++kc) {
        const int k0 = kc * KC;
        __syncthreads();                       // previous chunk consumed

        #pragma unroll
        for (int q = 0; q < 4; ++q) {
            const int idx = tid + q * 256;     // 1024 = 64 rows * 16 segs
            const int row = idx >> 4;
            const int seg = idx & 15;
            const int gk  = k0 + seg * 4;
            const float* xp = x + (size_t)(bid * BM + row) * DD + gk;
            float v0, v1, v2, v3;
            if (gk + 4 <= DD) {
                const float2 a = *(const float2*)xp;
                const float2 b2 = *(const float2*)(xp + 2);
                v0 = a.x; v1 = a.y; v2 = b2.x; v3 = b2.y;
            } else {
                v0 = (gk + 0 < DD) ? xp[0] : 0.f;
                v1 = (gk + 1 < DD) ? xp[1] : 0.f;
                v2 = (gk + 2 < DD) ? xp[2] : 0.f;
                v3 = (gk + 3 < DD) ? xp[3] : 0.f;
            }
            uint2 pk;
            pk.x = (unsigned)f2bf(v0) | ((unsigned)f2bf(v1) << 16);
            pk.y = (unsigned)f2bf(v2) | ((unsigned)f2bf(v3) << 16);
            *(uint2*)&a_s[row * PIT + seg * 4] = pk;
        }
        #pragma unroll
        for (int q = 0; q < 4; ++q) {
            const int idx = tid + q * 256;     // 896 = 112 rows * 8 b128
            if (idx < WR * 8) {
                const int wr = idx >> 3;
                const int c8 = idx & 7;
                const s16x8 v = *(const s16x8*)&w_ws[wr * KPAD + k0 + c8 * 8];
                *(s16x8*)&w_s[wr * PIT + c8 * 8] = v;
            }
        }
        __syncthreads();                       // tiles ready

        #pragma unroll
        for (int s = 0; s < 2; ++s) {          // 2 k-steps of 32
            const s16x8 af = *(const s16x8*)&a_s[(wv * 16 + c16) * PIT + s * 32 + kg];
            #pragma unroll
            for (int nt = 0; nt < 7; ++nt) {
                const s16x8 bf = *(const s16x8*)&w_s[(nt * 16 + c16) * PIT + s * 32 + kg];
                acc[nt] = __builtin_amdgcn_mfma_f32_16x16x32_bf16(af, bf, acc[nt], 0, 0, 0);
            }
        }
    }

    // C/D layout: col = l&15, row = (l>>4)*4 + reg  (m89-verified)
    const int rg = bid * BM + wv * 16 + ((ln >> 4) << 2);   // global C row base
    #pragma unroll
    for (int nt = 0; nt < 7; ++nt) {
        const int col = nt * 16 + c16;
        if (col < H1) {
            #pragma unroll
            for (int r = 0; r < 4; ++r)
                preT[(size_t)(rg + r) * H1 + col] = f2bf(acc[nt][r]);
        }
    }
}

// ============ kernel 2: fused two-layer scan + FC =============================
// r13 finding: scan ~105us = ~1260cy/step; audit -> AGPR-parked weights
// (VGPR_Count < live floats, no scratch) cost ~52 v_accvgpr_read/step, plus
// 52-FMA issue on the 2-way dot. Fix: 4-way dot split -> <=32 weight floats
// per thread (fits the compiler's ~48-64 VGPR comfort zone, no parking) and
// half the per-step issue. Alignment-correct quarters: l1 {0,28,52,76} over
// h1_s[104] (pads zeroed); l2 {0,32,64,96} over c_s[128]=[o1|h2|pad].
#define FMA4(W, PTR) { const float4 hv_ = *(const float4*)(PTR);            \
    a0 = fmaf((W).x, hv_.x, a0); a1 = fmaf((W).y, hv_.y, a1);               \
    a2 = fmaf((W).z, hv_.z, a2); a3 = fmaf((W).w, hv_.w, a3); }

#define CH 8        // steps per chunk
#define NCHK 25     // 200 / 8

__launch_bounds__(512, 1)
__global__ void scan_rnn(const unsigned short* __restrict__ preT,
                         const float* __restrict__ Whh1,
                         const float* __restrict__ bih1,
                         const float* __restrict__ bhh1,
                         const float* __restrict__ Wih2,
                         const float* __restrict__ Whh2,
                         const float* __restrict__ bih2,
                         const float* __restrict__ bhh2,
                         const float* __restrict__ Wfc,
                         const float* __restrict__ bfc,
                         const float* __restrict__ mask1,
                         const float* __restrict__ mask2,
                         float* __restrict__ out)
{
    __shared__ alignas(16) float h1_s[2][104];    // [100..103] zero pad
    __shared__ alignas(16) float c_s[2][128];     // [0..99]=o1,[100..119]=h2,pad
    __shared__ alignas(16) float h2f_s[H2];
    __shared__ alignas(16) float m_lds[2][CH * H1];   // mask1 chunks (f32)
    __shared__ alignas(16) float p_lds[2][CH * H1];   // pre1 chunks (f32)

    const int tid = threadIdx.x;
    const int b   = blockIdx.x;
    const float* m1b = mask1 + (size_t)b * TT * H1;
    const unsigned short* pTb = preT + (size_t)b * TT * H1;   // row-major [t][h]

    // l1: threads 0..399, neuron h = tid>>2, quarter q = tid&3
    const int h = tid >> 2;
    const int q = tid & 3;
    const bool l1t = (tid < 400);
    const int off1 = q * 24 + (q > 0 ? 4 : 0);            // {0,28,52,76}
    // l2: threads 416..495 (4-groups never cross wave bounds), k2/q2
    const bool l2t = (tid >= 416 && tid < 496);
    const int j2 = tid - 416;
    const int k2 = j2 >> 2;
    const int q2 = j2 & 3;

    float4 w00{}, w01{}, w02{}, w03{}, w04{}, w05{}, w06{}, w07{};
    float b1 = 0.f, b2 = 0.f;

    if (l1t) {
        // quarter q covers Whh1[h][off1 .. off1+27] (q0: 28 wts, else 24 + zero tail)
        const float* wr = Whh1 + h * H1 + off1;
        w00 = *(const float4*)(wr +  0); w01 = *(const float4*)(wr +  4);
        w02 = *(const float4*)(wr +  8); w03 = *(const float4*)(wr + 12);
        w04 = *(const float4*)(wr + 16); w05 = *(const float4*)(wr + 20);
        if (q == 0) { w06 = *(const float4*)(wr + 24); b1 = bih1[h] + bhh1[h]; }
    } else if (l2t) {
        // quarter q2 covers [q2*32, q2*32+32) of [Wih2 row | Whh2 row | pad]
        if (q2 < 3) {
            const float* wr = Wih2 + k2 * H1 + q2 * 32;
            w00 = *(const float4*)(wr +  0); w01 = *(const float4*)(wr +  4);
            w02 = *(const float4*)(wr +  8); w03 = *(const float4*)(wr + 12);
            w04 = *(const float4*)(wr + 16); w05 = *(const float4*)(wr + 20);
            w06 = *(const float4*)(wr + 24); w07 = *(const float4*)(wr + 28);
            if (q2 == 0) b2 = bih2[k2] + bhh2[k2];
        } else {
            w00 = *(const float4*)(Wih2 + k2 * H1 + 96);       // Wih2[96..99]
            const float* wh = Whh2 + k2 * H2;                  // 20 scalars (1-time)
            w01 = make_float4(wh[0],  wh[1],  wh[2],  wh[3]);
            w02 = make_float4(wh[4],  wh[5],  wh[6],  wh[7]);
            w03 = make_float4(wh[8],  wh[9],  wh[10], wh[11]);
            w04 = make_float4(wh[12], wh[13], wh[14], wh[15]);
            w05 = make_float4(wh[16], wh[17], wh[18], wh[19]);
            // w06, w07 stay 0 -> multiply the zeroed pad c_s[120..127]
        }
    }

    for (int i = tid; i < 104; i += 512) { h1_s[0][i] = 0.f; h1_s[1][i] = 0.f; }
    for (int i = tid; i < 128; i += 512) { c_s[0][i] = 0.f; c_s[1][i] = 0.f; }

    // stage chunk 0 into buffer 0 (t = 0..7): one wide load per thread
    if (tid < 200) {
        const float4 mv = *(const float4*)&m1b[tid * 4];
        *(float4*)&m_lds[0][tid * 4] = mv;
    } else if (tid < 300) {
        const s16x8 pv = *(const s16x8*)&pTb[(tid - 200) * 8];
        float* dst = &p_lds[0][(tid - 200) * 8];
        *(float4*)dst       = make_float4(bf2f(pv[0]), bf2f(pv[1]), bf2f(pv[2]), bf2f(pv[3]));
        *(float4*)(dst + 4) = make_float4(bf2f(pv[4]), bf2f(pv[5]), bf2f(pv[6]), bf2f(pv[7]));
    }
    __syncthreads();

    int buf = 0;
    for (int c = 0; c < NCHK; ++c) {
        const bool more = (c + 1 < NCHK);
        float4 mst{}; s16x8 pst{};

        #pragma unroll
        for (int u = 0; u < CH; ++u) {
            const int t = c * CH + u;
            const int cur = t & 1, nxt = cur ^ 1;

            if (u > 0) __syncthreads();        // chunk start already barriered

            if (u == 0 && more) {              // issue next chunk's loads
                const int base = (c + 1) * (CH * H1);
                if (tid < 200)      mst = *(const float4*)&m1b[base + tid * 4];
                else if (tid < 300) pst = *(const s16x8*)&pTb[base + (tid - 200) * 8];
            }

            if (l1t) {
                float a0 = (q == 0) ? (p_lds[buf][u * H1 + h] + b1) : 0.f;
                const float mv = (q == 1) ? m_lds[buf][u * H1 + h] : 0.f;
                float a1 = 0.f, a2 = 0.f, a3 = 0.f;
                const float* hb = &h1_s[cur][off1];
                FMA4(w00, hb +  0); FMA4(w01, hb +  4); FMA4(w02, hb +  8);
                FMA4(w03, hb + 12); FMA4(w04, hb + 16); FMA4(w05, hb + 20);
                FMA4(w06, hb + 24);            // q>0: zero wt x in-range/pad data
                float part = (a0 + a1) + (a2 + a3);
                part += __shfl_xor(part, 1);
                part += __shfl_xor(part, 2);
                const float tot = fmaxf(part, 0.f);          // h1(t)
                if (q == 0) h1_s[nxt][h] = tot;
                else if (q == 1) c_s[nxt][h] = tot * mv;     // o1(t)
            }

            if (l2t && t >= 1) {
                float a0 = (q2 == 0) ? b2 : 0.f;
                float a1 = 0.f, a2 = 0.f, a3 = 0.f;
                const float* cb = &c_s[cur][q2 * 32];
                FMA4(w00, cb +  0); FMA4(w01, cb +  4); FMA4(w02, cb +  8);
                FMA4(w03, cb + 12); FMA4(w04, cb + 16); FMA4(w05, cb + 20);
                FMA4(w06, cb + 24); FMA4(w07, cb + 28);
                float part = (a0 + a1) + (a2 + a3);
                part += __shfl_xor(part, 1);
                part += __shfl_xor(part, 2);
                const float h2v = fmaxf(part, 0.f);          // h2(t-1)
                if (q2 == 0) c_s[nxt][100 + k2] = h2v;
            }
        }

        // write staged chunk into the other buffer (latency fully elapsed)
        if (more) {
            if (tid < 200) {
                *(float4*)&m_lds[buf ^ 1][tid * 4] = mst;
            } else if (tid < 300) {
                float* dst = &p_lds[buf ^ 1][(tid - 200) * 8];
                *(float4*)dst       = make_float4(bf2f(pst[0]), bf2f(pst[1]), bf2f(pst[2]), bf2f(pst[3]));
                *(float4*)(dst + 4) = make_float4(bf2f(pst[4]), bf2f(pst[5]), bf2f(pst[6]), bf2f(pst[7]));
            }
            buf ^= 1;
        }
        __syncthreads();                        // chunk boundary barrier
    }

    // epilogue t = TT: layer2 computes h2(199) from o1(199), h2(198)
    {
        const int cur = TT & 1;                              // 0
        if (l2t) {
            float a0 = (q2 == 0) ? b2 : 0.f;
            float a1 = 0.f, a2 = 0.f, a3 = 0.f;
            const float* cb = &c_s[cur][q2 * 32];
            FMA4(w00, cb +  0); FMA4(w01, cb +  4); FMA4(w02, cb +  8);
            FMA4(w03, cb + 12); FMA4(w04, cb + 16); FMA4(w05, cb + 20);
            FMA4(w06, cb + 24); FMA4(w07, cb + 28);
            float part = (a0 + a1) + (a2 + a3);
            part += __shfl_xor(part, 1);
            part += __shfl_xor(part, 2);
            if (q2 == 0) h2f_s[k2] = fmaxf(part, 0.f);       // h2(199)
        }
        __syncthreads();
    }

    if (tid < NO) {
        const float* m2 = mask2 + ((size_t)b * TT + (TT - 1)) * H2;
        float s = bfc[tid];
        #pragma unroll
        for (int k = 0; k < H2; ++k)
            s = fmaf(Wfc[tid * H2 + k], h2f_s[k] * m2[k], s);
        out[b * NO + tid] = s;
    }
}

extern "C" void kernel_launch(void* const* d_in, const int* in_sizes, int n_in,
                              void* d_out, int out_size, void* d_ws, size_t ws_size,
                              hipStream_t stream) {
    const float* x     = (const float*)d_in[0];
    const float* Wih1  = (const float*)d_in[1];
    const float* Whh1  = (const float*)d_in[2];
    const float* bih1  = (const float*)d_in[3];
    const float* bhh1  = (const float*)d_in[4];
    const float* Wih2  = (const float*)d_in[5];
    const float* Whh2  = (const float*)d_in[6];
    const float* bih2  = (const float*)d_in[7];
    const float* bhh2  = (const float*)d_in[8];
    const float* Wfc   = (const float*)d_in[9];
    const float* bfc   = (const float*)d_in[10];
    const float* mask1 = (const float*)d_in[11];
    const float* mask2 = (const float*)d_in[12];
    float* out = (float*)d_out;

    unsigned short* preT = (unsigned short*)d_ws;                     // 10,240,000 B
    unsigned short* w_ws = (unsigned short*)((char*)d_ws + 10240000); //    286,720 B

    prep_w  <<<dim3((WR * KPAD / 4 + 255) / 256), dim3(256), 0, stream>>>(Wih1, w_ws);
    gemm_pre<<<dim3(GRID_A), dim3(256), 0, stream>>>(x, w_ws, preT);
    scan_rnn<<<dim3(NB), dim3(512), 0, stream>>>(preT, Whh1, bih1, bhh1,
                                                 Wih2, Whh2, bih2, bhh2,
                                                 Wfc, bfc, mask1, mask2, out);
}

// Round 15
// 206.625 us; speedup vs baseline: 1.1650x; 1.1650x over previous
//
#include <hip/hip_runtime.h>

#define NB 256      // batch
#define TT 200      // time steps
#define DD 1250     // input dim
#define H1 100
#define H2 20
#define NO 2

// ---- GEMM kernel geometry: C[51200,100] = Xflat[51200,1250] @ Wih1^T ----
#define BM 64                 // rows per block
#define GRID_A (51200 / BM)   // 800
#define KC 64                 // K-chunk
#define NCH 20                // 1280 / 64 (K padded)
#define WR 112                // padded W rows (7 n-tiles of 16)
#define PIT 72                // LDS row pitch in shorts
#define KPAD 1280

typedef __attribute__((ext_vector_type(4))) float f32x4;
typedef __attribute__((ext_vector_type(8))) short s16x8;

__device__ __forceinline__ unsigned short f2bf(float f) {
    unsigned u = __builtin_bit_cast(unsigned, f);
    u += 0x7FFFu + ((u >> 16) & 1u);          // round-to-nearest-even
    return (unsigned short)(u >> 16);
}
__device__ __forceinline__ float bf2f(unsigned short s) {
    unsigned u = ((unsigned)s) << 16;
    return __builtin_bit_cast(float, u);
}

// ============ kernel 0: Wih1 fp32[100][1250] -> bf16 [112][1280] (padded) ====
__global__ void prep_w(const float* __restrict__ Wih1, unsigned short* __restrict__ w_ws)
{
    const int idx = blockIdx.x * 256 + threadIdx.x;     // uint2 (4-short) granules
    if (idx >= WR * KPAD / 4) return;
    const int r  = idx / (KPAD / 4);
    const int k4 = (idx - r * (KPAD / 4)) * 4;
    unsigned short o[4];
    #pragma unroll
    for (int e = 0; e < 4; ++e) {
        const int k = k4 + e;
        o[e] = (r < H1 && k < DD) ? f2bf(Wih1[r * DD + k]) : (unsigned short)0;
    }
    uint2 pk;
    pk.x = (unsigned)o[0] | ((unsigned)o[1] << 16);
    pk.y = (unsigned)o[2] | ((unsigned)o[3] << 16);
    *(uint2*)&w_ws[r * KPAD + k4] = pk;
}

// ============ kernel 1: pre1[b*TT+t][h] (bf16, ROW-major) via MFMA ===========
// r14 analysis: old loop (barrier->stage->barrier->MFMA) paid one full HBM
// latency (~960cy) per chunk, serial within a block -> 2.56 TB/s. Now:
// double-buffered LDS + register ring (x 2-deep, W 1-deep), ONE barrier/chunk.
// x loads for chunk k+2 issue during chunk k's MFMA (~2 chunks of hiding);
// W (L2-hot) 1-deep. All staging in NAMED registers (r9 lesson).
__launch_bounds__(256, 4)
__global__ void gemm_pre(const float* __restrict__ x,
                         const unsigned short* __restrict__ w_ws,
                         unsigned short* __restrict__ preT)
{
    __shared__ __align__(16) unsigned short a_s[2][BM * PIT];   // 2 x  9216 B
    __shared__ __align__(16) unsigned short w_s[2][WR * PIT];   // 2 x 16128 B

    const int tid = threadIdx.x;
    const int bid = blockIdx.x;
    const int wv  = tid >> 6;
    const int ln  = tid & 63;
    const int c16 = ln & 15;
    const int kg  = (ln >> 4) << 3;

    f32x4 acc[7];
    #pragma unroll
    for (int i = 0; i < 7; ++i)
        #pragma unroll
        for (int c = 0; c < 4; ++c) acc[i][c] = 0.f;

    // x loader: 4 fixed (row,seg) slots per thread, chunk base k0
    auto ldx = [&](int k0, float4& v0q, float4& v1q, float4& v2q, float4& v3q) {
        #pragma unroll
        for (int q = 0; q < 4; ++q) {
            const int idx = tid + q * 256;
            const int row = idx >> 4;
            const int seg = idx & 15;
            const int gk  = k0 + seg * 4;
            const float* xp = x + (size_t)(bid * BM + row) * DD + gk;
            float4 v;
            if (gk + 4 <= DD) {
                const float2 a  = *(const float2*)xp;
                const float2 b2 = *(const float2*)(xp + 2);
                v = make_float4(a.x, a.y, b2.x, b2.y);
            } else {
                v.x = (gk + 0 < DD) ? xp[0] : 0.f;
                v.y = (gk + 1 < DD) ? xp[1] : 0.f;
                v.z = (gk + 2 < DD) ? xp[2] : 0.f;
                v.w = (gk + 3 < DD) ? xp[3] : 0.f;
            }
            if (q == 0) v0q = v; else if (q == 1) v1q = v;
            else if (q == 2) v2q = v; else v3q = v;
        }
    };
    auto stx = [&](int buf, float4 v0q, float4 v1q, float4 v2q, float4 v3q) {
        #pragma unroll
        for (int q = 0; q < 4; ++q) {
            const int idx = tid + q * 256;
            const int row = idx >> 4;
            const int seg = idx & 15;
            const float4 v = (q == 0) ? v0q : (q == 1) ? v1q : (q == 2) ? v2q : v3q;
            uint2 pk;
            pk.x = (unsigned)f2bf(v.x) | ((unsigned)f2bf(v.y) << 16);
            pk.y = (unsigned)f2bf(v.z) | ((unsigned)f2bf(v.w) << 16);
            *(uint2*)&a_s[buf][row * PIT + seg * 4] = pk;
        }
    };
    // W loader/storer: 896 slots (112 rows x 8 b128), predicated
    auto ldw = [&](int k0, s16x8& u0q, s16x8& u1q, s16x8& u2q, s16x8& u3q) {
        #pragma unroll
        for (int q = 0; q < 4; ++q) {
            const int idx = tid + q * 256;
            s16x8 u = {};
            if (idx < WR * 8) {
                const int wr = idx >> 3;
                const int c8 = idx & 7;
                u = *(const s16x8*)&w_ws[wr * KPAD + k0 + c8 * 8];
            }
            if (q == 0) u0q = u; else if (q == 1) u1q = u;
            else if (q == 2) u2q = u; else u3q = u;
        }
    };
    auto stw = [&](int buf, s16x8 u0q, s16x8 u1q, s16x8 u2q, s16x8 u3q) {
        #pragma unroll
        for (int q = 0; q < 4; ++q) {
            const int idx = tid + q * 256;
            if (idx < WR * 8) {
                const int wr = idx >> 3;
                const int c8 = idx & 7;
                const s16x8 u = (q == 0) ? u0q : (q == 1) ? u1q : (q == 2) ? u2q : u3q;
                *(s16x8*)&w_s[buf][wr * PIT + c8 * 8] = u;
            }
        }
    };

    float4 xa0, xa1, xa2, xa3, xb0, xb1, xb2, xb3;
    s16x8 wu0, wu1, wu2, wu3;
    ldx(0, xa0, xa1, xa2, xa3);                // chunk 0 -> slot A
    ldw(0, wu0, wu1, wu2, wu3);                // chunk 0 W
    ldx(KC, xb0, xb1, xb2, xb3);               // chunk 1 -> slot B

    for (int kc = 0; kc < NCH; ++kc) {
        const int buf = kc & 1;
        if (buf == 0) stx(0, xa0, xa1, xa2, xa3);
        else          stx(1, xb0, xb1, xb2, xb3);
        stw(buf, wu0, wu1, wu2, wu3);
        if (kc + 1 < NCH) ldw((kc + 1) * KC, wu0, wu1, wu2, wu3);  // W 1-deep
        __syncthreads();                       // publishes LDS[buf]

        #pragma unroll
        for (int s = 0; s < 2; ++s) {          // 2 k-steps of 32
            const s16x8 af = *(const s16x8*)&a_s[buf][(wv * 16 + c16) * PIT + s * 32 + kg];
            #pragma unroll
            for (int nt = 0; nt < 7; ++nt) {
                const s16x8 bf = *(const s16x8*)&w_s[buf][(nt * 16 + c16) * PIT + s * 32 + kg];
                acc[nt] = __builtin_amdgcn_mfma_f32_16x16x32_bf16(af, bf, acc[nt], 0, 0, 0);
            }
        }

        if (kc + 2 < NCH) {                    // x 2-deep: refill consumed slot
            if (buf == 0) ldx((kc + 2) * KC, xa0, xa1, xa2, xa3);
            else          ldx((kc + 2) * KC, xb0, xb1, xb2, xb3);
        }
    }

    // C/D layout: col = l&15, row = (l>>4)*4 + reg  (m89-verified)
    const int rg = bid * BM + wv * 16 + ((ln >> 4) << 2);   // global C row base
    #pragma unroll
    for (int nt = 0; nt < 7; ++nt) {
        const int col = nt * 16 + c16;
        if (col < H1) {
            #pragma unroll
            for (int r = 0; r < 4; ++r)
                preT[(size_t)(rg + r) * H1 + col] = f2bf(acc[nt][r]);
        }
    }
}

// ============ kernel 2: fused two-layer scan + FC (r13 exact, proven) ========
#define FMA4(W, PTR) { const float4 hv_ = *(const float4*)(PTR);            \
    a0 = fmaf((W).x, hv_.x, a0); a1 = fmaf((W).y, hv_.y, a1);               \
    a2 = fmaf((W).z, hv_.z, a2); a3 = fmaf((W).w, hv_.w, a3); }

#define CH 8        // steps per chunk
#define NCHK 25     // 200 / 8

__launch_bounds__(320, 1)
__global__ void scan_rnn(const unsigned short* __restrict__ preT,
                         const float* __restrict__ Whh1,
                         const float* __restrict__ bih1,
                         const float* __restrict__ bhh1,
                         const float* __restrict__ Wih2,
                         const float* __restrict__ Whh2,
                         const float* __restrict__ bih2,
                         const float* __restrict__ bhh2,
                         const float* __restrict__ Wfc,
                         const float* __restrict__ bfc,
                         const float* __restrict__ mask1,
                         const float* __restrict__ mask2,
                         float* __restrict__ out)
{
    __shared__ alignas(16) float h1_s[2][104];    // [100..103] zero pad
    __shared__ alignas(16) float c_s[2][120];     // [0..99]=o1, [100..119]=h2
    __shared__ alignas(16) float h2f_s[H2];
    __shared__ alignas(16) float m_lds[2][CH * H1];   // mask1 chunks (f32)
    __shared__ alignas(16) float p_lds[2][CH * H1];   // pre1 chunks (f32)

    const int tid = threadIdx.x;
    const int b   = blockIdx.x;
    const float* m1b = mask1 + (size_t)b * TT * H1;
    const unsigned short* pTb = preT + (size_t)b * TT * H1;   // row-major [t][h]

    const int h = tid >> 1;
    const int p = tid & 1;
    const bool l1t = (tid < 200);
    const bool l2t = (tid >= 256 && tid < 256 + 2 * H2);   // wave 4 only
    const int k2 = (tid - 256) >> 1;
    const int p3 = (tid - 256) & 1;

    float4 w00{}, w01{}, w02{}, w03{}, w04{}, w05{}, w06{}, w07{},
           w08{}, w09{}, w10{}, w11{}, w12{}, w13{}, w14{};
    float b1 = 0.f, b2 = 0.f;

    if (l1t) {
        const float* wr = Whh1 + h * H1 + p * 52;
        w00 = *(const float4*)(wr +  0); w01 = *(const float4*)(wr +  4);
        w02 = *(const float4*)(wr +  8); w03 = *(const float4*)(wr + 12);
        w04 = *(const float4*)(wr + 16); w05 = *(const float4*)(wr + 20);
        w06 = *(const float4*)(wr + 24); w07 = *(const float4*)(wr + 28);
        w08 = *(const float4*)(wr + 32); w09 = *(const float4*)(wr + 36);
        w10 = *(const float4*)(wr + 40); w11 = *(const float4*)(wr + 44);
        if (p == 0) { w12 = *(const float4*)(wr + 48); b1 = bih1[h] + bhh1[h]; }
    } else if (l2t) {
        if (p3 == 0) {
            const float* wr = Wih2 + k2 * H1;           // [0..59]
            w00 = *(const float4*)(wr +  0); w01 = *(const float4*)(wr +  4);
            w02 = *(const float4*)(wr +  8); w03 = *(const float4*)(wr + 12);
            w04 = *(const float4*)(wr + 16); w05 = *(const float4*)(wr + 20);
            w06 = *(const float4*)(wr + 24); w07 = *(const float4*)(wr + 28);
            w08 = *(const float4*)(wr + 32); w09 = *(const float4*)(wr + 36);
            w10 = *(const float4*)(wr + 40); w11 = *(const float4*)(wr + 44);
            w12 = *(const float4*)(wr + 48); w13 = *(const float4*)(wr + 52);
            w14 = *(const float4*)(wr + 56);
            b2 = bih2[k2] + bhh2[k2];
        } else {
            const float* wr = Wih2 + k2 * H1 + 60;      // [60..99]
            w00 = *(const float4*)(wr +  0); w01 = *(const float4*)(wr +  4);
            w02 = *(const float4*)(wr +  8); w03 = *(const float4*)(wr + 12);
            w04 = *(const float4*)(wr + 16); w05 = *(const float4*)(wr + 20);
            w06 = *(const float4*)(wr + 24); w07 = *(const float4*)(wr + 28);
            w08 = *(const float4*)(wr + 32); w09 = *(const float4*)(wr + 36);
            const float* wh = Whh2 + k2 * H2;           // h2 part [100..119]
            w10 = *(const float4*)(wh +  0); w11 = *(const float4*)(wh +  4);
            w12 = *(const float4*)(wh +  8); w13 = *(const float4*)(wh + 12);
            w14 = *(const float4*)(wh + 16);
        }
    }

    for (int i = tid; i < 104; i += 320) { h1_s[0][i] = 0.f; h1_s[1][i] = 0.f; }
    for (int i = tid; i < 120; i += 320) { c_s[0][i] = 0.f; c_s[1][i] = 0.f; }

    // stage chunk 0 into buffer 0 (t = 0..7): one wide load per thread
    if (tid < 200) {
        const float4 mv = *(const float4*)&m1b[tid * 4];
        *(float4*)&m_lds[0][tid * 4] = mv;
    } else if (tid < 300) {
        const s16x8 pv = *(const s16x8*)&pTb[(tid - 200) * 8];
        float* dst = &p_lds[0][(tid - 200) * 8];
        *(float4*)dst       = make_float4(bf2f(pv[0]), bf2f(pv[1]), bf2f(pv[2]), bf2f(pv[3]));
        *(float4*)(dst + 4) = make_float4(bf2f(pv[4]), bf2f(pv[5]), bf2f(pv[6]), bf2f(pv[7]));
    }
    __syncthreads();

    int buf = 0;
    for (int c = 0; c < NCHK; ++c) {
        const bool more = (c + 1 < NCHK);
        float4 mst{}; s16x8 pst{};

        #pragma unroll
        for (int u = 0; u < CH; ++u) {
            const int t = c * CH + u;
            const int cur = t & 1, nxt = cur ^ 1;

            if (u > 0) __syncthreads();        // chunk start already barriered

            if (u == 0 && more) {              // issue next chunk's loads
                const int base = (c + 1) * (CH * H1);
                if (tid < 200)      mst = *(const float4*)&m1b[base + tid * 4];
                else if (tid < 300) pst = *(const s16x8*)&pTb[base + (tid - 200) * 8];
            }

            if (l1t) {
                float a0 = (p == 0) ? (p_lds[buf][u * H1 + h] + b1) : 0.f;
                const float mv = (p == 1) ? m_lds[buf][u * H1 + h] : 0.f;
                float a1 = 0.f, a2 = 0.f, a3 = 0.f;
                const float* hb = &h1_s[cur][p * 52];
                FMA4(w00, hb +  0); FMA4(w01, hb +  4); FMA4(w02, hb +  8);
                FMA4(w03, hb + 12); FMA4(w04, hb + 16); FMA4(w05, hb + 20);
                FMA4(w06, hb + 24); FMA4(w07, hb + 28); FMA4(w08, hb + 32);
                FMA4(w09, hb + 36); FMA4(w10, hb + 40); FMA4(w11, hb + 44);
                FMA4(w12, hb + 48);
                float part = (a0 + a1) + (a2 + a3);
                float tot  = part + __shfl_xor(part, 1);
                tot = fmaxf(tot, 0.f);                       // h1(t)
                if (p == 0) h1_s[nxt][h] = tot;
                else        c_s[nxt][h] = tot * mv;          // o1(t)
            }

            if (l2t && t >= 1) {
                float a0 = (p3 == 0) ? b2 : 0.f;
                float a1 = 0.f, a2 = 0.f, a3 = 0.f;
                const float* cb = &c_s[cur][p3 * 60];
                FMA4(w00, cb +  0); FMA4(w01, cb +  4); FMA4(w02, cb +  8);
                FMA4(w03, cb + 12); FMA4(w04, cb + 16); FMA4(w05, cb + 20);
                FMA4(w06, cb + 24); FMA4(w07, cb + 28); FMA4(w08, cb + 32);
                FMA4(w09, cb + 36); FMA4(w10, cb + 40); FMA4(w11, cb + 44);
                FMA4(w12, cb + 48); FMA4(w13, cb + 52); FMA4(w14, cb + 56);
                float part = (a0 + a1) + (a2 + a3);
                part += __shfl_xor(part, 1);
                const float h2v = fmaxf(part, 0.f);          // h2(t-1)
                if (p3 == 0) c_s[nxt][100 + k2] = h2v;
            }
        }

        // write staged chunk into the other buffer (latency fully elapsed)
        if (more) {
            if (tid < 200) {
                *(float4*)&m_lds[buf ^ 1][tid * 4] = mst;
            } else if (tid < 300) {
                float* dst = &p_lds[buf ^ 1][(tid - 200) * 8];
                *(float4*)dst       = make_float4(bf2f(pst[0]), bf2f(pst[1]), bf2f(pst[2]), bf2f(pst[3]));
                *(float4*)(dst + 4) = make_float4(bf2f(pst[4]), bf2f(pst[5]), bf2f(pst[6]), bf2f(pst[7]));
            }
            buf ^= 1;
        }
        __syncthreads();                        // chunk boundary barrier
    }

    // epilogue t = TT: layer2 computes h2(199) from o1(199), h2(198)
    {
        const int cur = TT & 1;                              // 0
        if (l2t) {
            float a0 = (p3 == 0) ? b2 : 0.f;
            float a1 = 0.f, a2 = 0.f, a3 = 0.f;
            const float* cb = &c_s[cur][p3 * 60];
            FMA4(w00, cb +  0); FMA4(w01, cb +  4); FMA4(w02, cb +  8);
            FMA4(w03, cb + 12); FMA4(w04, cb + 16); FMA4(w05, cb + 20);
            FMA4(w06, cb + 24); FMA4(w07, cb + 28); FMA4(w08, cb + 32);
            FMA4(w09, cb + 36); FMA4(w10, cb + 40); FMA4(w11, cb + 44);
            FMA4(w12, cb + 48); FMA4(w13, cb + 52); FMA4(w14, cb + 56);
            float part = (a0 + a1) + (a2 + a3);
            part += __shfl_xor(part, 1);
            if (p3 == 0) h2f_s[k2] = fmaxf(part, 0.f);       // h2(199)
        }
        __syncthreads();
    }

    if (tid < NO) {
        const float* m2 = mask2 + ((size_t)b * TT + (TT - 1)) * H2;
        float s = bfc[tid];
        #pragma unroll
        for (int k = 0; k < H2; ++k)
            s = fmaf(Wfc[tid * H2 + k], h2f_s[k] * m2[k], s);
        out[b * NO + tid] = s;
    }
}

extern "C" void kernel_launch(void* const* d_in, const int* in_sizes, int n_in,
                              void* d_out, int out_size, void* d_ws, size_t ws_size,
                              hipStream_t stream) {
    const float* x     = (const float*)d_in[0];
    const float* Wih1  = (const float*)d_in[1];
    const float* Whh1  = (const float*)d_in[2];
    const float* bih1  = (const float*)d_in[3];
    const float* bhh1  = (const float*)d_in[4];
    const float* Wih2  = (const float*)d_in[5];
    const float* Whh2  = (const float*)d_in[6];
    const float* bih2  = (const float*)d_in[7];
    const float* bhh2  = (const float*)d_in[8];
    const float* Wfc   = (const float*)d_in[9];
    const float* bfc   = (const float*)d_in[10];
    const float* mask1 = (const float*)d_in[11];
    const float* mask2 = (const float*)d_in[12];
    float* out = (float*)d_out;

    unsigned short* preT = (unsigned short*)d_ws;                     // 10,240,000 B
    unsigned short* w_ws = (unsigned short*)((char*)d_ws + 10240000); //    286,720 B

    prep_w  <<<dim3((WR * KPAD / 4 + 255) / 256), dim3(256), 0, stream>>>(Wih1, w_ws);
    gemm_pre<<<dim3(GRID_A), dim3(256), 0, stream>>>(x, w_ws, preT);
    scan_rnn<<<dim3(NB), dim3(320), 0, stream>>>(preT, Whh1, bih1, bhh1,
                                                 Wih2, Whh2, bih2, bhh2,
                                                 Wfc, bfc, mask1, mask2, out);
}

// Round 16
// 169.535 us; speedup vs baseline: 1.4199x; 1.2188x over previous
//
#include <hip/hip_runtime.h>

#define NB 256      // batch
#define TT 200      // time steps
#define DD 1250     // input dim
#define H1 100
#define H2 20
#define NO 2

// ---- GEMM kernel geometry: C[51200,100] = Xflat[51200,1250] @ Wih1^T ----
#define BM 64                 // rows per block
#define GRID_A (51200 / BM)   // 800
#define KC 64                 // K-chunk
#define NCH 20                // 1280 / 64 (K padded)
#define WR 112                // padded W rows (7 n-tiles of 16)
#define KPAD 1280

typedef __attribute__((ext_vector_type(4))) float f32x4;
typedef __attribute__((ext_vector_type(8))) short s16x8;

__device__ __forceinline__ unsigned short f2bf(float f) {
    unsigned u = __builtin_bit_cast(unsigned, f);
    u += 0x7FFFu + ((u >> 16) & 1u);          // round-to-nearest-even
    return (unsigned short)(u >> 16);
}
__device__ __forceinline__ float bf2f(unsigned short s) {
    unsigned u = ((unsigned)s) << 16;
    return __builtin_bit_cast(float, u);
}

#define GLL(srcp, dstp) __builtin_amdgcn_global_load_lds( \
    (const __attribute__((address_space(1))) void*)(srcp), \
    (__attribute__((address_space(3))) void*)(dstp), 16, 0, 0)

// ============ kernel 0: Wih1 fp32[100][1250] -> bf16 [112][1280] (padded) ====
__global__ void prep_w(const float* __restrict__ Wih1, unsigned short* __restrict__ w_ws)
{
    const int idx = blockIdx.x * 256 + threadIdx.x;     // uint2 (4-short) granules
    if (idx >= WR * KPAD / 4) return;
    const int r  = idx / (KPAD / 4);
    const int k4 = (idx - r * (KPAD / 4)) * 4;
    unsigned short o[4];
    #pragma unroll
    for (int e = 0; e < 4; ++e) {
        const int k = k4 + e;
        o[e] = (r < H1 && k < DD) ? f2bf(Wih1[r * DD + k]) : (unsigned short)0;
    }
    uint2 pk;
    pk.x = (unsigned)o[0] | ((unsigned)o[1] << 16);
    pk.y = (unsigned)o[2] | ((unsigned)o[3] << 16);
    *(uint2*)&w_ws[r * KPAD + k4] = pk;
}

// ============ kernel 1: pre1[b*TT+t][h] via MFMA — global_load_lds staging ===
// r15 post-mortem: register-staged x/W kept every barrier's vmcnt(0) drain on
// fresh loads (VALU 10%, MFMA 4%, HBM 12%: all idle). Now staging is pure DMA:
// gll(16B) for x (fp32, cvt at A-read) and W (bf16). LDS dest must be linear
// (m104), so conflict-freedom comes from m201's pattern: pre-swizzled GLOBAL
// source + XOR-swizzled LDS read. A: seg^(row&15); W: c8^(row&7). Tail chunk
// 19 (crosses k=1250) via guarded register loads + swizzled ds_write, once.
__launch_bounds__(256, 4)
__global__ void gemm_pre(const float* __restrict__ x,
                         const unsigned short* __restrict__ w_ws,
                         unsigned short* __restrict__ preT)
{
    __shared__ __align__(16) float          a_sf[2][BM * 64];   // 32768 B
    __shared__ __align__(16) unsigned short w_sh[2][WR * 64];   // 28672 B

    const int tid = threadIdx.x;
    const int bid = blockIdx.x;
    const int wv  = tid >> 6;
    const int ln  = tid & 63;
    const int c16 = ln & 15;
    const int kgrp = ln >> 4;                 // 0..3

    f32x4 acc[7];
    #pragma unroll
    for (int i = 0; i < 7; ++i)
        #pragma unroll
        for (int c = 0; c < 4; ++c) acc[i][c] = 0.f;

    // ---- async A stage: 1024 slots x 16B; slot idx -> (row, phys seg) ------
    auto agll = [&](int k0, int buf) {
        #pragma unroll
        for (int q = 0; q < 4; ++q) {
            const int idx  = tid + q * 256;
            const int row  = idx >> 4;
            const int segp = idx & 15;
            const int segl = segp ^ (row & 15);            // inverse swizzle
            const float* src = x + (size_t)(bid * BM + row) * DD + k0 + segl * 4;
            GLL(src, &a_sf[buf][idx * 4]);
        }
    };
    // ---- async W stage: 896 slots x 16B; slot idx -> (row, phys c8) --------
    auto wgll = [&](int k0, int buf) {
        #pragma unroll
        for (int q = 0; q < 4; ++q) {
            const int idx = tid + q * 256;
            if (idx < WR * 8) {
                const int row = idx >> 3;
                const int c8p = idx & 7;
                const int c8l = c8p ^ (row & 7);           // inverse swizzle
                const unsigned short* src = w_ws + row * KPAD + k0 + c8l * 8;
                GLL(src, &w_sh[buf][idx * 8]);
            }
        }
    };

    auto mfma_chunk = [&](int buf) {
        #pragma unroll
        for (int s = 0; s < 2; ++s) {
            const int row_a = wv * 16 + c16;
            const int sb = s * 8 + kgrp * 2;               // logical seg base
            const int sp0 = (sb + 0) ^ (row_a & 15);
            const int sp1 = (sb + 1) ^ (row_a & 15);
            const float4 av0 = *(const float4*)&a_sf[buf][row_a * 64 + sp0 * 4];
            const float4 av1 = *(const float4*)&a_sf[buf][row_a * 64 + sp1 * 4];
            const s16x8 af = {
                (short)f2bf(av0.x), (short)f2bf(av0.y),
                (short)f2bf(av0.z), (short)f2bf(av0.w),
                (short)f2bf(av1.x), (short)f2bf(av1.y),
                (short)f2bf(av1.z), (short)f2bf(av1.w) };
            #pragma unroll
            for (int nt = 0; nt < 7; ++nt) {
                const int row_b = nt * 16 + c16;
                const int c8  = s * 4 + kgrp;              // logical
                const int c8p = c8 ^ (row_b & 7);
                const s16x8 bf = *(const s16x8*)&w_sh[buf][row_b * 64 + c8p * 8];
                acc[nt] = __builtin_amdgcn_mfma_f32_16x16x32_bf16(af, bf, acc[nt], 0, 0, 0);
            }
        }
    };

    // ---- tail chunk 19 (k 1216..1279, valid < 1250): guarded register loads
    float4 ta[4];
    #pragma unroll
    for (int q = 0; q < 4; ++q) {
        const int idx  = tid + q * 256;
        const int row  = idx >> 4;
        const int segl = idx & 15;
        const int gk   = 19 * KC + segl * 4;
        const float* xp = x + (size_t)(bid * BM + row) * DD + gk;
        float4 v;
        v.x = (gk + 0 < DD) ? xp[0] : 0.f;
        v.y = (gk + 1 < DD) ? xp[1] : 0.f;
        v.z = (gk + 2 < DD) ? xp[2] : 0.f;
        v.w = (gk + 3 < DD) ? xp[3] : 0.f;
        ta[q] = v;
    }

    agll(0, 0);
    wgll(0, 0);

    for (int kc = 0; kc < 19; ++kc) {
        const int buf = kc & 1;
        __syncthreads();                      // chunk kc resident in LDS[buf]
        if (kc + 1 < 19) agll((kc + 1) * KC, buf ^ 1);
        wgll((kc + 1) * KC, buf ^ 1);         // kc+1 == 19 ok (W padded to 1280)
        mfma_chunk(buf);
    }

    // tail: A via swizzled ds_write into buf 1 (free since chunk 17 consumed)
    #pragma unroll
    for (int q = 0; q < 4; ++q) {
        const int idx  = tid + q * 256;
        const int row  = idx >> 4;
        const int segl = idx & 15;
        const int sp   = segl ^ (row & 15);
        *(float4*)&a_sf[1][row * 64 + sp * 4] = ta[q];
    }
    __syncthreads();                          // publishes A-tail + W chunk 19
    mfma_chunk(1);

    // C/D layout: col = l&15, row = (l>>4)*4 + reg  (m89-verified)
    const int rg = bid * BM + wv * 16 + (kgrp << 2);        // global C row base
    #pragma unroll
    for (int nt = 0; nt < 7; ++nt) {
        const int col = nt * 16 + c16;
        if (col < H1) {
            #pragma unroll
            for (int r = 0; r < 4; ++r)
                preT[(size_t)(rg + r) * H1 + col] = f2bf(acc[nt][r]);
        }
    }
}

// ============ kernel 2: fused two-layer scan + FC (r13 exact, proven) ========
#define FMA4(W, PTR) { const float4 hv_ = *(const float4*)(PTR);            \
    a0 = fmaf((W).x, hv_.x, a0); a1 = fmaf((W).y, hv_.y, a1);               \
    a2 = fmaf((W).z, hv_.z, a2); a3 = fmaf((W).w, hv_.w, a3); }

#define CH 8        // steps per chunk
#define NCHK 25     // 200 / 8

__launch_bounds__(320, 1)
__global__ void scan_rnn(const unsigned short* __restrict__ preT,
                         const float* __restrict__ Whh1,
                         const float* __restrict__ bih1,
                         const float* __restrict__ bhh1,
                         const float* __restrict__ Wih2,
                         const float* __restrict__ Whh2,
                         const float* __restrict__ bih2,
                         const float* __restrict__ bhh2,
                         const float* __restrict__ Wfc,
                         const float* __restrict__ bfc,
                         const float* __restrict__ mask1,
                         const float* __restrict__ mask2,
                         float* __restrict__ out)
{
    __shared__ alignas(16) float h1_s[2][104];    // [100..103] zero pad
    __shared__ alignas(16) float c_s[2][120];     // [0..99]=o1, [100..119]=h2
    __shared__ alignas(16) float h2f_s[H2];
    __shared__ alignas(16) float m_lds[2][CH * H1];   // mask1 chunks (f32)
    __shared__ alignas(16) float p_lds[2][CH * H1];   // pre1 chunks (f32)

    const int tid = threadIdx.x;
    const int b   = blockIdx.x;
    const float* m1b = mask1 + (size_t)b * TT * H1;
    const unsigned short* pTb = preT + (size_t)b * TT * H1;   // row-major [t][h]

    const int h = tid >> 1;
    const int p = tid & 1;
    const bool l1t = (tid < 200);
    const bool l2t = (tid >= 256 && tid < 256 + 2 * H2);   // wave 4 only
    const int k2 = (tid - 256) >> 1;
    const int p3 = (tid - 256) & 1;

    float4 w00{}, w01{}, w02{}, w03{}, w04{}, w05{}, w06{}, w07{},
           w08{}, w09{}, w10{}, w11{}, w12{}, w13{}, w14{};
    float b1 = 0.f, b2 = 0.f;

    if (l1t) {
        const float* wr = Whh1 + h * H1 + p * 52;
        w00 = *(const float4*)(wr +  0); w01 = *(const float4*)(wr +  4);
        w02 = *(const float4*)(wr +  8); w03 = *(const float4*)(wr + 12);
        w04 = *(const float4*)(wr + 16); w05 = *(const float4*)(wr + 20);
        w06 = *(const float4*)(wr + 24); w07 = *(const float4*)(wr + 28);
        w08 = *(const float4*)(wr + 32); w09 = *(const float4*)(wr + 36);
        w10 = *(const float4*)(wr + 40); w11 = *(const float4*)(wr + 44);
        if (p == 0) { w12 = *(const float4*)(wr + 48); b1 = bih1[h] + bhh1[h]; }
    } else if (l2t) {
        if (p3 == 0) {
            const float* wr = Wih2 + k2 * H1;           // [0..59]
            w00 = *(const float4*)(wr +  0); w01 = *(const float4*)(wr +  4);
            w02 = *(const float4*)(wr +  8); w03 = *(const float4*)(wr + 12);
            w04 = *(const float4*)(wr + 16); w05 = *(const float4*)(wr + 20);
            w06 = *(const float4*)(wr + 24); w07 = *(const float4*)(wr + 28);
            w08 = *(const float4*)(wr + 32); w09 = *(const float4*)(wr + 36);
            w10 = *(const float4*)(wr + 40); w11 = *(const float4*)(wr + 44);
            w12 = *(const float4*)(wr + 48); w13 = *(const float4*)(wr + 52);
            w14 = *(const float4*)(wr + 56);
            b2 = bih2[k2] + bhh2[k2];
        } else {
            const float* wr = Wih2 + k2 * H1 + 60;      // [60..99]
            w00 = *(const float4*)(wr +  0); w01 = *(const float4*)(wr +  4);
            w02 = *(const float4*)(wr +  8); w03 = *(const float4*)(wr + 12);
            w04 = *(const float4*)(wr + 16); w05 = *(const float4*)(wr + 20);
            w06 = *(const float4*)(wr + 24); w07 = *(const float4*)(wr + 28);
            w08 = *(const float4*)(wr + 32); w09 = *(const float4*)(wr + 36);
            const float* wh = Whh2 + k2 * H2;           // h2 part [100..119]
            w10 = *(const float4*)(wh +  0); w11 = *(const float4*)(wh +  4);
            w12 = *(const float4*)(wh +  8); w13 = *(const float4*)(wh + 12);
            w14 = *(const float4*)(wh + 16);
        }
    }

    for (int i = tid; i < 104; i += 320) { h1_s[0][i] = 0.f; h1_s[1][i] = 0.f; }
    for (int i = tid; i < 120; i += 320) { c_s[0][i] = 0.f; c_s[1][i] = 0.f; }

    // stage chunk 0 into buffer 0 (t = 0..7): one wide load per thread
    if (tid < 200) {
        const float4 mv = *(const float4*)&m1b[tid * 4];
        *(float4*)&m_lds[0][tid * 4] = mv;
    } else if (tid < 300) {
        const s16x8 pv = *(const s16x8*)&pTb[(tid - 200) * 8];
        float* dst = &p_lds[0][(tid - 200) * 8];
        *(float4*)dst       = make_float4(bf2f(pv[0]), bf2f(pv[1]), bf2f(pv[2]), bf2f(pv[3]));
        *(float4*)(dst + 4) = make_float4(bf2f(pv[4]), bf2f(pv[5]), bf2f(pv[6]), bf2f(pv[7]));
    }
    __syncthreads();

    int buf = 0;
    for (int c = 0; c < NCHK; ++c) {
        const bool more = (c + 1 < NCHK);
        float4 mst{}; s16x8 pst{};

        #pragma unroll
        for (int u = 0; u < CH; ++u) {
            const int t = c * CH + u;
            const int cur = t & 1, nxt = cur ^ 1;

            if (u > 0) __syncthreads();        // chunk start already barriered

            if (u == 0 && more) {              // issue next chunk's loads
                const int base = (c + 1) * (CH * H1);
                if (tid < 200)      mst = *(const float4*)&m1b[base + tid * 4];
                else if (tid < 300) pst = *(const s16x8*)&pTb[base + (tid - 200) * 8];
            }

            if (l1t) {
                float a0 = (p == 0) ? (p_lds[buf][u * H1 + h] + b1) : 0.f;
                const float mv = (p == 1) ? m_lds[buf][u * H1 + h] : 0.f;
                float a1 = 0.f, a2 = 0.f, a3 = 0.f;
                const float* hb = &h1_s[cur][p * 52];
                FMA4(w00, hb +  0); FMA4(w01, hb +  4); FMA4(w02, hb +  8);
                FMA4(w03, hb + 12); FMA4(w04, hb + 16); FMA4(w05, hb + 20);
                FMA4(w06, hb + 24); FMA4(w07, hb + 28); FMA4(w08, hb + 32);
                FMA4(w09, hb + 36); FMA4(w10, hb + 40); FMA4(w11, hb + 44);
                FMA4(w12, hb + 48);
                float part = (a0 + a1) + (a2 + a3);
                float tot  = part + __shfl_xor(part, 1);
                tot = fmaxf(tot, 0.f);                       // h1(t)
                if (p == 0) h1_s[nxt][h] = tot;
                else        c_s[nxt][h] = tot * mv;          // o1(t)
            }

            if (l2t && t >= 1) {
                float a0 = (p3 == 0) ? b2 : 0.f;
                float a1 = 0.f, a2 = 0.f, a3 = 0.f;
                const float* cb = &c_s[cur][p3 * 60];
                FMA4(w00, cb +  0); FMA4(w01, cb +  4); FMA4(w02, cb +  8);
                FMA4(w03, cb + 12); FMA4(w04, cb + 16); FMA4(w05, cb + 20);
                FMA4(w06, cb + 24); FMA4(w07, cb + 28); FMA4(w08, cb + 32);
                FMA4(w09, cb + 36); FMA4(w10, cb + 40); FMA4(w11, cb + 44);
                FMA4(w12, cb + 48); FMA4(w13, cb + 52); FMA4(w14, cb + 56);
                float part = (a0 + a1) + (a2 + a3);
                part += __shfl_xor(part, 1);
                const float h2v = fmaxf(part, 0.f);          // h2(t-1)
                if (p3 == 0) c_s[nxt][100 + k2] = h2v;
            }
        }

        // write staged chunk into the other buffer (latency fully elapsed)
        if (more) {
            if (tid < 200) {
                *(float4*)&m_lds[buf ^ 1][tid * 4] = mst;
            } else if (tid < 300) {
                float* dst = &p_lds[buf ^ 1][(tid - 200) * 8];
                *(float4*)dst       = make_float4(bf2f(pst[0]), bf2f(pst[1]), bf2f(pst[2]), bf2f(pst[3]));
                *(float4*)(dst + 4) = make_float4(bf2f(pst[4]), bf2f(pst[5]), bf2f(pst[6]), bf2f(pst[7]));
            }
            buf ^= 1;
        }
        __syncthreads();                        // chunk boundary barrier
    }

    // epilogue t = TT: layer2 computes h2(199) from o1(199), h2(198)
    {
        const int cur = TT & 1;                              // 0
        if (l2t) {
            float a0 = (p3 == 0) ? b2 : 0.f;
            float a1 = 0.f, a2 = 0.f, a3 = 0.f;
            const float* cb = &c_s[cur][p3 * 60];
            FMA4(w00, cb +  0); FMA4(w01, cb +  4); FMA4(w02, cb +  8);
            FMA4(w03, cb + 12); FMA4(w04, cb + 16); FMA4(w05, cb + 20);
            FMA4(w06, cb + 24); FMA4(w07, cb + 28); FMA4(w08, cb + 32);
            FMA4(w09, cb + 36); FMA4(w10, cb + 40); FMA4(w11, cb + 44);
            FMA4(w12, cb + 48); FMA4(w13, cb + 52); FMA4(w14, cb + 56);
            float part = (a0 + a1) + (a2 + a3);
            part += __shfl_xor(part, 1);
            if (p3 == 0) h2f_s[k2] = fmaxf(part, 0.f);       // h2(199)
        }
        __syncthreads();
    }

    if (tid < NO) {
        const float* m2 = mask2 + ((size_t)b * TT + (TT - 1)) * H2;
        float s = bfc[tid];
        #pragma unroll
        for (int k = 0; k < H2; ++k)
            s = fmaf(Wfc[tid * H2 + k], h2f_s[k] * m2[k], s);
        out[b * NO + tid] = s;
    }
}

extern "C" void kernel_launch(void* const* d_in, const int* in_sizes, int n_in,
                              void* d_out, int out_size, void* d_ws, size_t ws_size,
                              hipStream_t stream) {
    const float* x     = (const float*)d_in[0];
    const float* Wih1  = (const float*)d_in[1];
    const float* Whh1  = (const float*)d_in[2];
    const float* bih1  = (const float*)d_in[3];
    const float* bhh1  = (const float*)d_in[4];
    const float* Wih2  = (const float*)d_in[5];
    const float* Whh2  = (const float*)d_in[6];
    const float* bih2  = (const float*)d_in[7];
    const float* bhh2  = (const float*)d_in[8];
    const float* Wfc   = (const float*)d_in[9];
    const float* bfc   = (const float*)d_in[10];
    const float* mask1 = (const float*)d_in[11];
    const float* mask2 = (const float*)d_in[12];
    float* out = (float*)d_out;

    unsigned short* preT = (unsigned short*)d_ws;                     // 10,240,000 B
    unsigned short* w_ws = (unsigned short*)((char*)d_ws + 10240000); //    286,720 B

    prep_w  <<<dim3((WR * KPAD / 4 + 255) / 256), dim3(256), 0, stream>>>(Wih1, w_ws);
    gemm_pre<<<dim3(GRID_A), dim3(256), 0, stream>>>(x, w_ws, preT);
    scan_rnn<<<dim3(NB), dim3(320), 0, stream>>>(preT, Whh1, bih1, bhh1,
                                                 Wih2, Whh2, bih2, bhh2,
                                                 Wfc, bfc, mask1, mask2, out);
}